// Round 12
// baseline (183.450 us; speedup 1.0000x reference)
//
#include <hip/hip_runtime.h>
#include <math.h>

// GPT attention block: B=8, T=1024, E=768, H=12, D=64. fp32 in/out.
// Round 22 (= R21 resubmit; infra "container failed twice", kernel audit
// clean — same situation as R7->R8 which cleared on resubmit).
// Flash v8b = merged paired-QK (K-fragments read once per knt, feed both
// q-tiles — bitwise-identical math to v7) + v7's manual +0x8000 pack
// (cvt_pk truncates on gfx950 -> absmax fail in R10).
// QKV = R15 128x192 2-phase (measured best). Proj = R5 template. Prep same.

#define B_ 8
#define T_ 1024
#define E_ 768
#define H_ 12
#define D_ 64
#define E3 (3 * E_)

typedef __attribute__((ext_vector_type(8))) short bf16x8;
typedef __attribute__((ext_vector_type(4))) float f32x4;

#define SCALE 0.18033688f // 0.125 * log2(e)

__device__ __forceinline__ unsigned short f2bf(float f) {
    unsigned int u = __builtin_bit_cast(unsigned int, f);
    u += 0x7fffu + ((u >> 16) & 1u);   // RNE
    return (unsigned short)(u >> 16);
}

__device__ __forceinline__ void async_copy16(void* lds, const void* g) {
    __builtin_amdgcn_global_load_lds(
        (const __attribute__((address_space(1))) void*)g,
        (__attribute__((address_space(3))) void*)lds, 16, 0, 0);
}

// ---------------- fused prep: x->bf16, w_attn^T, w_proj^T ----------------
#define NCVT 6144                 // (8192*768/4)/256
#define NTA  (72 * 24)            // (E3/32) x (E_/32)
#define NTP  (24 * 24)            // (E_/32) x (E_/32)

__device__ __forceinline__ void transpose_tile(
    const float* __restrict__ W, unsigned short* __restrict__ Wt,
    int K, int N, int gx, int gy, unsigned short (*tile)[33])
{
    const int n0 = gx * 32, k0 = gy * 32;
    const int tx = threadIdx.x & 31, ty = threadIdx.x >> 5;
    #pragma unroll
    for (int i = 0; i < 4; ++i)
        tile[ty + i * 8][tx] = f2bf(W[(size_t)(k0 + ty + i * 8) * N + n0 + tx]);
    __syncthreads();
    #pragma unroll
    for (int i = 0; i < 4; ++i)
        Wt[(size_t)(n0 + ty + i * 8) * K + k0 + tx] = tile[tx][ty + i * 8];
}

__global__ __launch_bounds__(256) void prep_kernel(
    const float* __restrict__ x, unsigned short* __restrict__ x_bf,
    const float* __restrict__ w_attn, unsigned short* __restrict__ wat,
    const float* __restrict__ w_proj, unsigned short* __restrict__ wpt)
{
    __shared__ unsigned short tile[32][33];
    const int bid = blockIdx.x;
    if (bid < NCVT) {
        const int i = bid * 256 + threadIdx.x;
        float4 f = ((const float4*)x)[i];
        ushort4 o;
        o.x = f2bf(f.x); o.y = f2bf(f.y); o.z = f2bf(f.z); o.w = f2bf(f.w);
        ((ushort4*)x_bf)[i] = o;
    } else if (bid < NCVT + NTA) {
        const int t = bid - NCVT;
        transpose_tile(w_attn, wat, E_, E3, t % 72, t / 72, tile);
    } else {
        const int t = bid - NCVT - NTA;
        transpose_tile(w_proj, wpt, E_, E_, t % 24, t / 24, tile);
    }
}

// ---------------- QKV GEMM: 128x192 tile, 2-phase counted-vmcnt (R15) ----------------
__global__ __launch_bounds__(512, 4) void gemm_qkv_128x192(
    const unsigned short* __restrict__ A,   // [8192,768] bf16
    const unsigned short* __restrict__ Wt,  // [2304,768] bf16
    const float* __restrict__ bias,
    unsigned short* __restrict__ C,         // [8192,2304] bf16 (Q,K regions)
    unsigned short* __restrict__ vt)        // [B*H*64,1024] bf16
{
    constexpr int K = 768;
    constexpr int N = E3;
    constexpr int NKT = 12;                 // K / 64

    extern __shared__ unsigned short lds[];

    const int tid  = threadIdx.x;
    const int lane = tid & 63;
    const int w    = tid >> 6;          // 0..7
    const int wm   = w >> 2;            // 0..1
    const int wn   = w & 3;             // 0..3
    const int n16  = lane & 15;
    const int quad = lane >> 4;
    const int l7   = lane & 7;
    const int lrow = lane >> 3;
    const int lcol = (l7 ^ lrow) * 8;   // pre-swizzled source column group

    const int lin  = blockIdx.x;
    const int s    = lin >> 3;
    const int by   = (lin & 7) * 8 + s / 12;
    const int bx   = s % 12;
    const int bm = by * 128, bn = bx * 192;

    const unsigned short* Asrc = A  + (size_t)(bm + lrow) * K + lcol;
    const unsigned short* Bsrc = Wt + (size_t)(bn + lrow) * K + lcol;

    auto stage = [&](int bi, int kt) {
        unsigned short* ab = lds + (bi ? 8192 : 0);
        unsigned short* bb = lds + 16384 + (bi ? 12288 : 0);
        #pragma unroll
        for (int i = 0; i < 2; ++i) {
            const int c = w * 2 + i;
            async_copy16(&ab[c * 512], Asrc + (size_t)(c * 8) * K + kt * 64);
        }
        #pragma unroll
        for (int i = 0; i < 3; ++i) {
            const int c = w * 3 + i;
            async_copy16(&bb[c * 512], Bsrc + (size_t)(c * 8) * K + kt * 64);
        }
    };

    f32x4 acc[4][3] = {};

#define BARR  __builtin_amdgcn_s_barrier()
#define VM5   asm volatile("s_waitcnt vmcnt(5)" ::: "memory")
#define VM0   asm volatile("s_waitcnt vmcnt(0)" ::: "memory")
#define PRI1  __builtin_amdgcn_s_setprio(1)
#define PRI0  __builtin_amdgcn_s_setprio(0)

    stage(0, 0);

    #pragma unroll 1
    for (int u = 0; u < NKT; ++u) {
        const int bi = u & 1;
        const unsigned short* ab = lds + (bi ? 8192 : 0);
        const unsigned short* bb = lds + 16384 + (bi ? 12288 : 0);
        if (u < NKT - 1) {
            stage(bi ^ 1, u + 1);
            VM5;
        } else {
            VM0;
        }
        BARR;

        #pragma unroll
        for (int kc = 0; kc < 2; ++kc) {
            bf16x8 af[4], bf[3];
            #pragma unroll
            for (int m = 0; m < 4; ++m) {
                const int r = wm * 16 + m * 32 + n16;
                af[m] = *(const bf16x8*)&ab[r * 64 + (((kc * 4 + quad) ^ (r & 7)) * 8)];
            }
            #pragma unroll
            for (int n = 0; n < 3; ++n) {
                const int r = wn * 16 + n * 64 + n16;
                bf[n] = *(const bf16x8*)&bb[r * 64 + (((kc * 4 + quad) ^ (r & 7)) * 8)];
            }
            PRI1;
            #pragma unroll
            for (int m = 0; m < 4; ++m)
                #pragma unroll
                for (int n = 0; n < 3; ++n)
                    acc[m][n] = __builtin_amdgcn_mfma_f32_16x16x32_bf16(
                        af[m], bf[n], acc[m][n], 0, 0, 0);
            PRI0;
        }
        BARR;
    }

#undef VM5
#undef VM0

    if (bx >= 8) {
        #pragma unroll
        for (int m = 0; m < 4; ++m) {
            const int tt = bm + wm * 16 + m * 32 + quad * 4;
            const size_t bb2 = (size_t)(tt >> 10) * 768;
            const int tin = tt & 1023;
            #pragma unroll
            for (int n = 0; n < 3; ++n) {
                const int col = bn + wn * 16 + n * 64 + n16;
                const int ch = col - 1536;
                const float bv = bias[col];
                ushort4 o4;
                o4.x = f2bf(acc[m][n][0] + bv);
                o4.y = f2bf(acc[m][n][1] + bv);
                o4.z = f2bf(acc[m][n][2] + bv);
                o4.w = f2bf(acc[m][n][3] + bv);
                *(ushort4*)&vt[(bb2 + ch) * 1024 + tin] = o4;
            }
        }
    } else {
        const bool scale_q = bx < 4;
        #pragma unroll
        for (int m = 0; m < 4; ++m) {
            #pragma unroll
            for (int r = 0; r < 4; ++r) {
                const size_t rowoff = (size_t)(bm + wm * 16 + m * 32 + quad * 4 + r) * N;
                #pragma unroll
                for (int n = 0; n < 3; ++n) {
                    const int col = bn + wn * 16 + n * 64 + n16;
                    float v = acc[m][n][r] + bias[col];
                    if (scale_q) v *= SCALE;
                    C[rowoff + col] = f2bf(v);
                }
            }
        }
    }
}

// ---------------- bf16 MFMA GEMM (proj, exact R5 config) ----------------
template <typename OutT, int MODE, int BM, int BN, int WR, int WC>
__global__ __launch_bounds__(256) void gemm_mfma_kernel(
    const unsigned short* __restrict__ A,   // [M,K] bf16
    const unsigned short* __restrict__ Wt,  // [N,K] bf16
    const float* __restrict__ bias,
    OutT* __restrict__ C,
    unsigned short* __restrict__ vt,
    int M, int N, int K)
{
    constexpr int MT = BM / WR / 16;
    constexpr int NT = BN / WC / 16;
    constexpr int CA = BM / 32;
    constexpr int CB = BN / 32;
    constexpr int QBX = 768 / BN;
    constexpr int VBX = 1536 / BN;

    __shared__ unsigned short Abuf[BM * 64];
    __shared__ unsigned short Bbuf[BN * 64];

    const int tid = threadIdx.x;
    const int lane = tid & 63;
    const int w = tid >> 6;
    const int n16 = lane & 15;
    const int quad = lane >> 4;

    const int nbx = gridDim.x;
    const int lin = blockIdx.y * nbx + blockIdx.x;
    const int band_sz = 8 * nbx;
    const int band = lin / band_sz;
    const int rr = lin % band_sz;
    const int bm = (band * 8 + (rr & 7)) * BM;
    const int bx = rr >> 3;
    const int bn = bx * BN;

    const int wmbase = (w / WC) * (BM / WR);
    const int wnbase = (w % WC) * (BN / WC);

    const int lrow = lane >> 3;
    const int lcol = ((lane & 7) ^ lrow) * 8;

    f32x4 acc[MT][NT] = {};

    for (int k0 = 0; k0 < K; k0 += 64) {
        __syncthreads();
        #pragma unroll
        for (int i = 0; i < CA; ++i) {
            const int c = w * CA + i;
            const int row = c * 8 + lrow;
            async_copy16(&Abuf[c * 512], A + (size_t)(bm + row) * K + k0 + lcol);
        }
        #pragma unroll
        for (int i = 0; i < CB; ++i) {
            const int c = w * CB + i;
            const int row = c * 8 + lrow;
            async_copy16(&Bbuf[c * 512], Wt + (size_t)(bn + row) * K + k0 + lcol);
        }
        __syncthreads();

        #pragma unroll
        for (int kc = 0; kc < 2; ++kc) {
            bf16x8 af[MT], bf[NT];
            #pragma unroll
            for (int mt = 0; mt < MT; ++mt) {
                const int r = wmbase + mt * 16 + n16;
                af[mt] = *(const bf16x8*)&Abuf[r * 64 + ((kc * 4 + quad) ^ (r & 7)) * 8];
            }
            #pragma unroll
            for (int nt = 0; nt < NT; ++nt) {
                const int r = wnbase + nt * 16 + n16;
                bf[nt] = *(const bf16x8*)&Bbuf[r * 64 + ((kc * 4 + quad) ^ (r & 7)) * 8];
            }
            #pragma unroll
            for (int mt = 0; mt < MT; ++mt)
                #pragma unroll
                for (int nt = 0; nt < NT; ++nt)
                    acc[mt][nt] = __builtin_amdgcn_mfma_f32_16x16x32_bf16(
                        af[mt], bf[nt], acc[mt][nt], 0, 0, 0);
        }
    }

    if (MODE == 1 && bx >= VBX) {
        #pragma unroll
        for (int mt = 0; mt < MT; ++mt) {
            const int tt = bm + wmbase + mt * 16 + quad * 4;
            const size_t bb = (size_t)(tt >> 10) * 768;
            const int tin = tt & 1023;
            #pragma unroll
            for (int nt = 0; nt < NT; ++nt) {
                const int col = bn + wnbase + nt * 16 + n16;
                const int ch = col - 1536;
                const float bv = bias[col];
                ushort4 o4;
                o4.x = f2bf(acc[mt][nt][0] + bv);
                o4.y = f2bf(acc[mt][nt][1] + bv);
                o4.z = f2bf(acc[mt][nt][2] + bv);
                o4.w = f2bf(acc[mt][nt][3] + bv);
                *(ushort4*)&vt[(bb + ch) * 1024 + tin] = o4;
            }
        }
        return;
    }

    const bool scale_q = (MODE == 1) && (bx < QBX);
    #pragma unroll
    for (int mt = 0; mt < MT; ++mt) {
        #pragma unroll
        for (int r = 0; r < 4; ++r) {
            const size_t rowoff = (size_t)(bm + wmbase + mt * 16 + quad * 4 + r) * N;
            #pragma unroll
            for (int nt = 0; nt < NT; ++nt) {
                const int col = bn + wnbase + nt * 16 + n16;
                float v = acc[mt][nt][r] + bias[col];
                if (scale_q) v *= SCALE;
                if constexpr (sizeof(OutT) == 2) C[rowoff + col] = (OutT)f2bf(v);
                else                             C[rowoff + col] = (OutT)v;
            }
        }
    }
}

// ---------------- Flash attention v8b: merged paired-QK, manual pack ----------------
#define BKEY 128

__global__ __launch_bounds__(256, 3) void flash_attn_kernel(
    const unsigned short* __restrict__ qkv,
    const unsigned short* __restrict__ vt,   // [(b*H+h)*64+d][1024] bf16
    unsigned short* __restrict__ out)
{
    __shared__ __align__(16) unsigned short Ks[2][BKEY * 64];   // double-buffered K
    __shared__ __align__(16) unsigned short Vts[64 * BKEY];     // single-buffered V^T

    const int tid = threadIdx.x;
    const int idx = blockIdx.x;
    const int xcd = idx & 7;
    const int j   = idx >> 3;           // 0..95
    const int head = xcd * 12 + (j % 12);
    const int p    = j / 12;            // 0..7
    const int h = head % H_;
    const int b = head / H_;

    const int lane = tid & 63;
    const int w    = tid >> 6;
    const int n16  = lane & 15;
    const int quad = lane >> 4;

    const size_t base = (size_t)b * T_ * E3;
    const unsigned short* qbase = qkv + base + h * D_;          // pre-scaled q
    const unsigned short* kbase = qkv + base + E_ + h * D_;
    const unsigned short* vtb   = vt + (size_t)(b * H_ + h) * 64 * 1024;

    const int lrow = lane >> 3;
    const int lcol = ((lane & 7) ^ lrow) * 8;
    const int vr4 = lane >> 4;
    const int vc  = lane & 15;

    const int qtA = p, qtB = 15 - p;
    const int nIterA = (qtA + 2) >> 1;
    const int nIterB = (qtB + 2) >> 1;
    const int wqA = qtA * 64 + w * 16;
    const int wqB = qtB * 64 + w * 16;

    const unsigned short* qrpA = qbase + (size_t)(wqA + n16) * E3 + quad * 8;
    bf16x8 qfA0 = *(const bf16x8*)qrpA;
    bf16x8 qfA1 = *(const bf16x8*)(qrpA + 32);
    const unsigned short* qrpB = qbase + (size_t)(wqB + n16) * E3 + quad * 8;
    bf16x8 qfB0 = *(const bf16x8*)qrpB;
    bf16x8 qfB1 = *(const bf16x8*)(qrpB + 32);

    f32x4 oA[4] = {}, oB[4] = {};
    float lsA = 0.f, lsB = 0.f;

    const int sLo = n16 + 32 * (quad & 1);
    const int sHi = sLo + 16;
    const bool hiSel = quad >= 2;

    auto stageK = [&](int t) {
        unsigned short* dst = Ks[t & 1];
        const int k0 = t * BKEY;
        #pragma unroll
        for (int i = 0; i < 4; ++i) {
            const int c = w * 4 + i;
            const int row = c * 8 + lrow;
            async_copy16(&dst[c * 512], kbase + (size_t)(k0 + row) * E3 + lcol);
        }
    };
    auto stageV = [&](int t) {
        const int k0 = t * BKEY;
        #pragma unroll
        for (int i = 0; i < 4; ++i) {
            const int jj = w * 4 + i;
            const int row = 4 * jj + vr4;
            async_copy16(&Vts[4 * jj * BKEY],
                         vtb + (size_t)row * 1024 + k0 + ((vc ^ (row & 15)) * 8));
        }
    };

    // softmax + PV on a precomputed S^T block (QK already done)
    auto soft_pv = [&](f32x4* s, f32x4* o, float& lsum, int wave_q_min, int k0,
                       bool doMid, bool notLast) {
        int knt_lim = ((wave_q_min + 15 - k0) >> 4) + 1;
        if (knt_lim > 8) knt_lim = 8;
        const int ks_lim = (knt_lim + 1) >> 1;
        const int nkp = ks_lim * 2;
        int Ab2 = wave_q_min - k0 - 15;
        int kfull = Ab2 < 0 ? 0 : (Ab2 >> 4) + 1;
        if (kfull > 8) kfull = 8;

        const int qcol = wave_q_min + n16;           // this lane's q row

        // causal mask
        #pragma unroll
        for (int knt = 0; knt < 8; ++knt) {
            if (knt >= kfull && knt < nkp) {
                const int krow = k0 + knt * 16 + quad * 4;
                #pragma unroll
                for (int r = 0; r < 4; ++r) {
                    float v = (knt < knt_lim) ? s[knt][r] : -1e30f;
                    if (krow + r > qcol) v = -1e30f;
                    s[knt][r] = v;
                }
            }
        }

        // exp2, lsum, manual +0x8000 pack (near-unbiased; cvt_pk truncates)
        unsigned int e0[8], e1[8];
        #pragma unroll
        for (int knt = 0; knt < 8; ++knt) {
            if (knt < nkp) {
                float pv0 = __builtin_amdgcn_exp2f(s[knt][0]);
                float pv1 = __builtin_amdgcn_exp2f(s[knt][1]);
                float pv2 = __builtin_amdgcn_exp2f(s[knt][2]);
                float pv3 = __builtin_amdgcn_exp2f(s[knt][3]);
                lsum += (pv0 + pv1) + (pv2 + pv3);
                unsigned int u0 = __builtin_bit_cast(unsigned int, pv0);
                unsigned int u1 = __builtin_bit_cast(unsigned int, pv1);
                unsigned int u2 = __builtin_bit_cast(unsigned int, pv2);
                unsigned int u3 = __builtin_bit_cast(unsigned int, pv3);
                e0[knt] = ((u0 + 0x8000u) >> 16) | ((u1 + 0x8000u) & 0xffff0000u);
                e1[knt] = ((u2 + 0x8000u) >> 16) | ((u3 + 0x8000u) & 0xffff0000u);
            }
        }

        if (doMid) {
            // own V[t] (and older) landed; K[t+1] may stay in flight
            if (notLast) asm volatile("s_waitcnt vmcnt(4)" ::: "memory");
            else         asm volatile("s_waitcnt vmcnt(0)" ::: "memory");
            __builtin_amdgcn_s_barrier();
        }

        // O += P V : build A-frag via cross-quad shfl
        #pragma unroll
        for (int ks = 0; ks < 4; ++ks) {
            if (ks < ks_lim) {
                const int kA = 2 * ks, kB = 2 * ks + 1;
                unsigned int a0 = (unsigned)__shfl((int)e0[kA], sLo);
                unsigned int a1 = (unsigned)__shfl((int)e1[kA], sLo);
                unsigned int a2 = (unsigned)__shfl((int)e0[kA], sHi);
                unsigned int a3 = (unsigned)__shfl((int)e1[kA], sHi);
                unsigned int b0 = (unsigned)__shfl((int)e0[kB], sLo);
                unsigned int b1 = (unsigned)__shfl((int)e1[kB], sLo);
                unsigned int b2 = (unsigned)__shfl((int)e0[kB], sHi);
                unsigned int b3 = (unsigned)__shfl((int)e1[kB], sHi);
                uint4 pu;
                pu.x = hiSel ? b0 : a0;
                pu.y = hiSel ? b1 : a1;
                pu.z = hiSel ? b2 : a2;
                pu.w = hiSel ? b3 : a3;
                bf16x8 pf = __builtin_bit_cast(bf16x8, pu);
                #pragma unroll
                for (int dt = 0; dt < 4; ++dt) {
                    const int row = dt * 16 + n16;
                    bf16x8 vf = *(const bf16x8*)&Vts[row * BKEY +
                                    (((ks * 4 + quad) ^ n16) * 8)];
                    o[dt] = __builtin_amdgcn_mfma_f32_16x16x32_bf16(pf, vf, o[dt], 0, 0, 0);
                }
            }
        }
    };

    stageK(0);
    asm volatile("s_waitcnt vmcnt(0)" ::: "memory");
    __builtin_amdgcn_s_barrier();

    for (int it = 0; it < nIterB; ++it) {
        const int k0 = it * BKEY;
        const bool notLast = (it + 1 < nIterB);
        const bool doA = (it < nIterA);

        stageV(it);
        if (notLast) stageK(it + 1);
        const unsigned short* Kb = Ks[it & 1];

        // ---- merged QK: read each K-fragment once, feed both q-tiles ----
        int limB = ((wqB + 15 - k0) >> 4) + 1;
        if (limB > 8) limB = 8;
        int limA = 0;
        if (doA) {
            limA = ((wqA + 15 - k0) >> 4) + 1;
            if (limA > 8) limA = 8;
            if (limA < 0) limA = 0;
        }

        f32x4 sB[8], sA[8];
        #pragma unroll
        for (int knt = 0; knt < 8; ++knt) {
            if (knt < limB) {
                const int r = knt * 16 + n16;
                bf16x8 kf0 = *(const bf16x8*)&Kb[r * 64 + ((0 + quad) ^ (r & 7)) * 8];
                bf16x8 kf1 = *(const bf16x8*)&Kb[r * 64 + ((4 + quad) ^ (r & 7)) * 8];
                f32x4 aB = {0.f, 0.f, 0.f, 0.f};
                aB = __builtin_amdgcn_mfma_f32_16x16x32_bf16(kf0, qfB0, aB, 0, 0, 0);
                aB = __builtin_amdgcn_mfma_f32_16x16x32_bf16(kf1, qfB1, aB, 0, 0, 0);
                sB[knt] = aB;
                if (knt < limA) {        // limA <= limB always (wqA < wqB)
                    f32x4 aA = {0.f, 0.f, 0.f, 0.f};
                    aA = __builtin_amdgcn_mfma_f32_16x16x32_bf16(kf0, qfA0, aA, 0, 0, 0);
                    aA = __builtin_amdgcn_mfma_f32_16x16x32_bf16(kf1, qfA1, aA, 0, 0, 0);
                    sA[knt] = aA;
                }
            }
        }

        soft_pv(sB, oB, lsB, wqB, k0, true, notLast);
        if (doA) soft_pv(sA, oA, lsA, wqA, k0, false, notLast);

        asm volatile("s_waitcnt vmcnt(0)" ::: "memory");
        __builtin_amdgcn_s_barrier();
    }

    lsA += __shfl_xor(lsA, 16); lsA += __shfl_xor(lsA, 32);
    lsB += __shfl_xor(lsB, 16); lsB += __shfl_xor(lsB, 32);

    #pragma unroll
    for (int r = 0; r < 4; ++r) {
        const float invA = 1.f / __shfl(lsA, quad * 4 + r);
        unsigned short* orowA = out + ((size_t)b * T_ + wqA + quad * 4 + r) * E_ + h * D_;
        #pragma unroll
        for (int dt = 0; dt < 4; ++dt)
            orowA[dt * 16 + n16] = f2bf(oA[dt][r] * invA);
        const float invB = 1.f / __shfl(lsB, quad * 4 + r);
        unsigned short* orowB = out + ((size_t)b * T_ + wqB + quad * 4 + r) * E_ + h * D_;
        #pragma unroll
        for (int dt = 0; dt < 4; ++dt)
            orowB[dt * 16 + n16] = f2bf(oB[dt][r] * invB);
    }
}

extern "C" void kernel_launch(void* const* d_in, const int* in_sizes, int n_in,
                              void* d_out, int out_size, void* d_ws, size_t ws_size,
                              hipStream_t stream)
{
    const float* x      = (const float*)d_in[0];
    const float* w_attn = (const float*)d_in[1];
    const float* b_attn = (const float*)d_in[2];
    const float* w_proj = (const float*)d_in[3];
    const float* b_proj = (const float*)d_in[4];
    float* out = (float*)d_out;

    const int M = B_ * T_;  // 8192

    unsigned short* x_bf   = (unsigned short*)d_ws;           // [M,E]
    unsigned short* wat    = x_bf + (size_t)M * E_;           // [3E,E]
    unsigned short* wpt    = wat + (size_t)E3 * E_;           // [E,E]
    unsigned short* qkv_bf = wpt + (size_t)E_ * E_;           // [M,3E] (V region unused)
    unsigned short* att_bf = qkv_bf + (size_t)M * E3;         // [M,E]
    unsigned short* vt_bf  = att_bf + (size_t)M * E_;         // [B*H*64,1024]

    static bool attr_set = false;
    if (!attr_set) {
        (void)hipFuncSetAttribute((const void*)gemm_qkv_128x192,
                                  hipFuncAttributeMaxDynamicSharedMemorySize, 81920);
        attr_set = true;
    }

    prep_kernel<<<NCVT + NTA + NTP, 256, 0, stream>>>(x, x_bf, w_attn, wat, w_proj, wpt);

    gemm_qkv_128x192<<<dim3(768), dim3(512), 81920, stream>>>(
        x_bf, wat, b_attn, qkv_bf, vt_bf);

    flash_attn_kernel<<<B_ * H_ * 8, 256, 0, stream>>>(qkv_bf, vt_bf, att_bf);

    gemm_mfma_kernel<float, 0, 64, 128, 2, 2>
        <<<dim3(E_ / 128, M / 64), 256, 0, stream>>>(
        att_bf, wpt, b_proj, out, nullptr, M, E_, E_);
}

// Round 13
// 168.233 us; speedup vs baseline: 1.0904x; 1.0904x over previous
//
#include <hip/hip_runtime.h>
#include <math.h>

// GPT attention block: B=8, T=1024, E=768, H=12, D=64. fp32 in/out.
// Round 23: byte-exact revert to the R5/round-15 configuration — the
// best-measured state (167.2us). QKV = 128x192 2-phase counted-vmcnt
// (41.7us measured); flash = v7 (pipelined LDS staging, no Ps, <=41us);
// proj = R5 gemm_mfma template; prep unchanged. R12's merged-QK flash
// (v8b) regressed flash to 47.4us (held S-tiles serialize the softmax
// register chains) and is reverted.

#define B_ 8
#define T_ 1024
#define E_ 768
#define H_ 12
#define D_ 64
#define E3 (3 * E_)

typedef __attribute__((ext_vector_type(8))) short bf16x8;
typedef __attribute__((ext_vector_type(4))) float f32x4;

#define SCALE 0.18033688f // 0.125 * log2(e)

__device__ __forceinline__ unsigned short f2bf(float f) {
    unsigned int u = __builtin_bit_cast(unsigned int, f);
    u += 0x7fffu + ((u >> 16) & 1u);   // RNE
    return (unsigned short)(u >> 16);
}

__device__ __forceinline__ void async_copy16(void* lds, const void* g) {
    __builtin_amdgcn_global_load_lds(
        (const __attribute__((address_space(1))) void*)g,
        (__attribute__((address_space(3))) void*)lds, 16, 0, 0);
}

// ---------------- fused prep: x->bf16, w_attn^T, w_proj^T ----------------
#define NCVT 6144                 // (8192*768/4)/256
#define NTA  (72 * 24)            // (E3/32) x (E_/32)
#define NTP  (24 * 24)            // (E_/32) x (E_/32)

__device__ __forceinline__ void transpose_tile(
    const float* __restrict__ W, unsigned short* __restrict__ Wt,
    int K, int N, int gx, int gy, unsigned short (*tile)[33])
{
    const int n0 = gx * 32, k0 = gy * 32;
    const int tx = threadIdx.x & 31, ty = threadIdx.x >> 5;
    #pragma unroll
    for (int i = 0; i < 4; ++i)
        tile[ty + i * 8][tx] = f2bf(W[(size_t)(k0 + ty + i * 8) * N + n0 + tx]);
    __syncthreads();
    #pragma unroll
    for (int i = 0; i < 4; ++i)
        Wt[(size_t)(n0 + ty + i * 8) * K + k0 + tx] = tile[tx][ty + i * 8];
}

__global__ __launch_bounds__(256) void prep_kernel(
    const float* __restrict__ x, unsigned short* __restrict__ x_bf,
    const float* __restrict__ w_attn, unsigned short* __restrict__ wat,
    const float* __restrict__ w_proj, unsigned short* __restrict__ wpt)
{
    __shared__ unsigned short tile[32][33];
    const int bid = blockIdx.x;
    if (bid < NCVT) {
        const int i = bid * 256 + threadIdx.x;
        float4 f = ((const float4*)x)[i];
        ushort4 o;
        o.x = f2bf(f.x); o.y = f2bf(f.y); o.z = f2bf(f.z); o.w = f2bf(f.w);
        ((ushort4*)x_bf)[i] = o;
    } else if (bid < NCVT + NTA) {
        const int t = bid - NCVT;
        transpose_tile(w_attn, wat, E_, E3, t % 72, t / 72, tile);
    } else {
        const int t = bid - NCVT - NTA;
        transpose_tile(w_proj, wpt, E_, E_, t % 24, t / 24, tile);
    }
}

// ---------------- QKV GEMM: 128x192 tile, 2-phase counted-vmcnt ----------------
__global__ __launch_bounds__(512, 4) void gemm_qkv_128x192(
    const unsigned short* __restrict__ A,   // [8192,768] bf16
    const unsigned short* __restrict__ Wt,  // [2304,768] bf16
    const float* __restrict__ bias,
    unsigned short* __restrict__ C,         // [8192,2304] bf16 (Q,K regions)
    unsigned short* __restrict__ vt)        // [B*H*64,1024] bf16
{
    constexpr int K = 768;
    constexpr int N = E3;
    constexpr int NKT = 12;                 // K / 64

    // layout: [buf0 A 8192][buf1 A 8192][buf0 B 12288][buf1 B 12288] (ushorts)
    extern __shared__ unsigned short lds[];

    const int tid  = threadIdx.x;
    const int lane = tid & 63;
    const int w    = tid >> 6;          // 0..7
    const int wm   = w >> 2;            // 0..1
    const int wn   = w & 3;             // 0..3
    const int n16  = lane & 15;
    const int quad = lane >> 4;
    const int l7   = lane & 7;
    const int lrow = lane >> 3;
    const int lcol = (l7 ^ lrow) * 8;   // pre-swizzled source column group

    // XCD-chunked swizzle: 768 blocks = 8 XCDs x 96; XCD x covers rows of
    // batch x (by = 8x + s/12) -> preserves flash's b-affinity.
    const int lin  = blockIdx.x;
    const int s    = lin >> 3;
    const int by   = (lin & 7) * 8 + s / 12;
    const int bx   = s % 12;
    const int bm = by * 128, bn = bx * 192;

    const unsigned short* Asrc = A  + (size_t)(bm + lrow) * K + lcol;
    const unsigned short* Bsrc = Wt + (size_t)(bn + lrow) * K + lcol;

    auto stage = [&](int bi, int kt) {
        unsigned short* ab = lds + (bi ? 8192 : 0);
        unsigned short* bb = lds + 16384 + (bi ? 12288 : 0);
        #pragma unroll
        for (int i = 0; i < 2; ++i) {
            const int c = w * 2 + i;                  // 0..15 (8 rows each)
            async_copy16(&ab[c * 512], Asrc + (size_t)(c * 8) * K + kt * 64);
        }
        #pragma unroll
        for (int i = 0; i < 3; ++i) {
            const int c = w * 3 + i;                  // 0..23
            async_copy16(&bb[c * 512], Bsrc + (size_t)(c * 8) * K + kt * 64);
        }
    };

    f32x4 acc[4][3] = {};

#define BARR  __builtin_amdgcn_s_barrier()
#define VM5   asm volatile("s_waitcnt vmcnt(5)" ::: "memory")
#define VM0   asm volatile("s_waitcnt vmcnt(0)" ::: "memory")
#define PRI1  __builtin_amdgcn_s_setprio(1)
#define PRI0  __builtin_amdgcn_s_setprio(0)

    stage(0, 0);                        // prologue: tile 0 -> buf0 (5 ops)

    #pragma unroll 1
    for (int u = 0; u < NKT; ++u) {
        const int bi = u & 1;
        const unsigned short* ab = lds + (bi ? 8192 : 0);
        const unsigned short* bb = lds + 16384 + (bi ? 12288 : 0);
        if (u < NKT - 1) {
            stage(bi ^ 1, u + 1);       // 5 ops -> other buffer
            VM5;                        // tile u's 5 ops landed; u+1 in flight
        } else {
            VM0;
        }
        BARR;                           // buf[u] valid for all waves

        #pragma unroll
        for (int kc = 0; kc < 2; ++kc) {
            bf16x8 af[4], bf[3];
            #pragma unroll
            for (int m = 0; m < 4; ++m) {
                const int r = wm * 16 + m * 32 + n16;
                af[m] = *(const bf16x8*)&ab[r * 64 + (((kc * 4 + quad) ^ (r & 7)) * 8)];
            }
            #pragma unroll
            for (int n = 0; n < 3; ++n) {
                const int r = wn * 16 + n * 64 + n16;
                bf[n] = *(const bf16x8*)&bb[r * 64 + (((kc * 4 + quad) ^ (r & 7)) * 8)];
            }
            PRI1;
            #pragma unroll
            for (int m = 0; m < 4; ++m)
                #pragma unroll
                for (int n = 0; n < 3; ++n)
                    acc[m][n] = __builtin_amdgcn_mfma_f32_16x16x32_bf16(
                        af[m], bf[n], acc[m][n], 0, 0, 0);
            PRI0;
        }
        BARR;                           // close reads before next overwrite
    }

#undef VM5
#undef VM0

    // ---- epilogue: col-tiles 0-3 = Q (scaled), 4-7 = K, 8-11 = V -> vt ----
    if (bx >= 8) {
        #pragma unroll
        for (int m = 0; m < 4; ++m) {
            const int tt = bm + wm * 16 + m * 32 + quad * 4;
            const size_t bb2 = (size_t)(tt >> 10) * 768;
            const int tin = tt & 1023;
            #pragma unroll
            for (int n = 0; n < 3; ++n) {
                const int col = bn + wn * 16 + n * 64 + n16;
                const int ch = col - 1536;
                const float bv = bias[col];
                ushort4 o4;
                o4.x = f2bf(acc[m][n][0] + bv);
                o4.y = f2bf(acc[m][n][1] + bv);
                o4.z = f2bf(acc[m][n][2] + bv);
                o4.w = f2bf(acc[m][n][3] + bv);
                *(ushort4*)&vt[(bb2 + ch) * 1024 + tin] = o4;
            }
        }
    } else {
        const bool scale_q = bx < 4;
        #pragma unroll
        for (int m = 0; m < 4; ++m) {
            #pragma unroll
            for (int r = 0; r < 4; ++r) {
                const size_t rowoff = (size_t)(bm + wm * 16 + m * 32 + quad * 4 + r) * N;
                #pragma unroll
                for (int n = 0; n < 3; ++n) {
                    const int col = bn + wn * 16 + n * 64 + n16;
                    float v = acc[m][n][r] + bias[col];
                    if (scale_q) v *= SCALE;
                    C[rowoff + col] = f2bf(v);
                }
            }
        }
    }
}

// ---------------- bf16 MFMA GEMM (proj, exact R5 config) ----------------
template <typename OutT, int MODE, int BM, int BN, int WR, int WC>
__global__ __launch_bounds__(256) void gemm_mfma_kernel(
    const unsigned short* __restrict__ A,   // [M,K] bf16
    const unsigned short* __restrict__ Wt,  // [N,K] bf16
    const float* __restrict__ bias,
    OutT* __restrict__ C,
    unsigned short* __restrict__ vt,
    int M, int N, int K)
{
    constexpr int MT = BM / WR / 16;
    constexpr int NT = BN / WC / 16;
    constexpr int CA = BM / 32;
    constexpr int CB = BN / 32;
    constexpr int QBX = 768 / BN;
    constexpr int VBX = 1536 / BN;

    __shared__ unsigned short Abuf[BM * 64];
    __shared__ unsigned short Bbuf[BN * 64];

    const int tid = threadIdx.x;
    const int lane = tid & 63;
    const int w = tid >> 6;
    const int n16 = lane & 15;
    const int quad = lane >> 4;

    const int nbx = gridDim.x;
    const int lin = blockIdx.y * nbx + blockIdx.x;
    const int band_sz = 8 * nbx;
    const int band = lin / band_sz;
    const int rr = lin % band_sz;
    const int bm = (band * 8 + (rr & 7)) * BM;
    const int bx = rr >> 3;
    const int bn = bx * BN;

    const int wmbase = (w / WC) * (BM / WR);
    const int wnbase = (w % WC) * (BN / WC);

    const int lrow = lane >> 3;
    const int lcol = ((lane & 7) ^ lrow) * 8;

    f32x4 acc[MT][NT] = {};

    for (int k0 = 0; k0 < K; k0 += 64) {
        __syncthreads();
        #pragma unroll
        for (int i = 0; i < CA; ++i) {
            const int c = w * CA + i;
            const int row = c * 8 + lrow;
            async_copy16(&Abuf[c * 512], A + (size_t)(bm + row) * K + k0 + lcol);
        }
        #pragma unroll
        for (int i = 0; i < CB; ++i) {
            const int c = w * CB + i;
            const int row = c * 8 + lrow;
            async_copy16(&Bbuf[c * 512], Wt + (size_t)(bn + row) * K + k0 + lcol);
        }
        __syncthreads();

        #pragma unroll
        for (int kc = 0; kc < 2; ++kc) {
            bf16x8 af[MT], bf[NT];
            #pragma unroll
            for (int mt = 0; mt < MT; ++mt) {
                const int r = wmbase + mt * 16 + n16;
                af[mt] = *(const bf16x8*)&Abuf[r * 64 + ((kc * 4 + quad) ^ (r & 7)) * 8];
            }
            #pragma unroll
            for (int nt = 0; nt < NT; ++nt) {
                const int r = wnbase + nt * 16 + n16;
                bf[nt] = *(const bf16x8*)&Bbuf[r * 64 + ((kc * 4 + quad) ^ (r & 7)) * 8];
            }
            #pragma unroll
            for (int mt = 0; mt < MT; ++mt)
                #pragma unroll
                for (int nt = 0; nt < NT; ++nt)
                    acc[mt][nt] = __builtin_amdgcn_mfma_f32_16x16x32_bf16(
                        af[mt], bf[nt], acc[mt][nt], 0, 0, 0);
        }
    }

    if (MODE == 1 && bx >= VBX) {
        #pragma unroll
        for (int mt = 0; mt < MT; ++mt) {
            const int tt = bm + wmbase + mt * 16 + quad * 4;
            const size_t bb = (size_t)(tt >> 10) * 768;
            const int tin = tt & 1023;
            #pragma unroll
            for (int nt = 0; nt < NT; ++nt) {
                const int col = bn + wnbase + nt * 16 + n16;
                const int ch = col - 1536;
                const float bv = bias[col];
                ushort4 o4;
                o4.x = f2bf(acc[mt][nt][0] + bv);
                o4.y = f2bf(acc[mt][nt][1] + bv);
                o4.z = f2bf(acc[mt][nt][2] + bv);
                o4.w = f2bf(acc[mt][nt][3] + bv);
                *(ushort4*)&vt[(bb + ch) * 1024 + tin] = o4;
            }
        }
        return;
    }

    const bool scale_q = (MODE == 1) && (bx < QBX);
    #pragma unroll
    for (int mt = 0; mt < MT; ++mt) {
        #pragma unroll
        for (int r = 0; r < 4; ++r) {
            const size_t rowoff = (size_t)(bm + wmbase + mt * 16 + quad * 4 + r) * N;
            #pragma unroll
            for (int nt = 0; nt < NT; ++nt) {
                const int col = bn + wnbase + nt * 16 + n16;
                float v = acc[mt][nt][r] + bias[col];
                if (scale_q) v *= SCALE;
                if constexpr (sizeof(OutT) == 2) C[rowoff + col] = (OutT)f2bf(v);
                else                             C[rowoff + col] = (OutT)v;
            }
        }
    }
}

// ---------------- Flash attention v7: pipelined LDS staging, no Ps ----------------
#define BKEY 128

__global__ __launch_bounds__(256, 3) void flash_attn_kernel(
    const unsigned short* __restrict__ qkv,
    const unsigned short* __restrict__ vt,   // [(b*H+h)*64+d][1024] bf16
    unsigned short* __restrict__ out)
{
    __shared__ __align__(16) unsigned short Ks[2][BKEY * 64];   // double-buffered K
    __shared__ __align__(16) unsigned short Vts[64 * BKEY];     // single-buffered V^T

    const int tid = threadIdx.x;
    const int idx = blockIdx.x;
    const int xcd = idx & 7;
    const int j   = idx >> 3;           // 0..95
    const int head = xcd * 12 + (j % 12);
    const int p    = j / 12;            // 0..7
    const int h = head % H_;
    const int b = head / H_;

    const int lane = tid & 63;
    const int w    = tid >> 6;
    const int n16  = lane & 15;
    const int quad = lane >> 4;

    const size_t base = (size_t)b * T_ * E3;
    const unsigned short* qbase = qkv + base + h * D_;          // pre-scaled q
    const unsigned short* kbase = qkv + base + E_ + h * D_;
    const unsigned short* vtb   = vt + (size_t)(b * H_ + h) * 64 * 1024;

    const int lrow = lane >> 3;
    const int lcol = ((lane & 7) ^ lrow) * 8;
    const int vr4 = lane >> 4;
    const int vc  = lane & 15;

    const int qtA = p, qtB = 15 - p;
    const int nIterA = (qtA + 2) >> 1;
    const int nIterB = (qtB + 2) >> 1;
    const int wqA = qtA * 64 + w * 16;
    const int wqB = qtB * 64 + w * 16;

    const unsigned short* qrpA = qbase + (size_t)(wqA + n16) * E3 + quad * 8;
    bf16x8 qfA0 = *(const bf16x8*)qrpA;
    bf16x8 qfA1 = *(const bf16x8*)(qrpA + 32);
    const unsigned short* qrpB = qbase + (size_t)(wqB + n16) * E3 + quad * 8;
    bf16x8 qfB0 = *(const bf16x8*)qrpB;
    bf16x8 qfB1 = *(const bf16x8*)(qrpB + 32);

    f32x4 oA[4] = {}, oB[4] = {};
    float lsA = 0.f, lsB = 0.f;

    const int sLo = n16 + 32 * (quad & 1);
    const int sHi = sLo + 16;
    const bool hiSel = quad >= 2;

    auto stageK = [&](int t) {                 // K tile t -> Ks[t&1] (4 loads)
        unsigned short* dst = Ks[t & 1];
        const int k0 = t * BKEY;
        #pragma unroll
        for (int i = 0; i < 4; ++i) {
            const int c = w * 4 + i;
            const int row = c * 8 + lrow;
            async_copy16(&dst[c * 512], kbase + (size_t)(k0 + row) * E3 + lcol);
        }
    };
    auto stageV = [&](int t) {                 // V tile t -> Vts (4 loads)
        const int k0 = t * BKEY;
        #pragma unroll
        for (int i = 0; i < 4; ++i) {
            const int jj = w * 4 + i;
            const int row = 4 * jj + vr4;
            async_copy16(&Vts[4 * jj * BKEY],
                         vtb + (size_t)row * 1024 + k0 + ((vc ^ (row & 15)) * 8));
        }
    };

    auto phase = [&](bf16x8 qf0, bf16x8 qf1, f32x4* o, float& lsum,
                     int wave_q_min, int k0, const unsigned short* Kb,
                     bool doMid, bool notLast) {
        int knt_lim = ((wave_q_min + 15 - k0) >> 4) + 1;
        if (knt_lim > 8) knt_lim = 8;
        const int ks_lim = (knt_lim + 1) >> 1;
        const int nkp = ks_lim * 2;
        int Ab2 = wave_q_min - k0 - 15;
        int kfull = Ab2 < 0 ? 0 : (Ab2 >> 4) + 1;
        if (kfull > 8) kfull = 8;

        const int qcol = wave_q_min + n16;           // this lane's q row

        f32x4 s[8];
        #pragma unroll
        for (int knt = 0; knt < 8; ++knt) {
            if (knt < knt_lim) {
                const int r = knt * 16 + n16;
                bf16x8 kf0 = *(const bf16x8*)&Kb[r * 64 + ((0 + quad) ^ (r & 7)) * 8];
                bf16x8 kf1 = *(const bf16x8*)&Kb[r * 64 + ((4 + quad) ^ (r & 7)) * 8];
                f32x4 acc = {0.f, 0.f, 0.f, 0.f};
                acc = __builtin_amdgcn_mfma_f32_16x16x32_bf16(kf0, qf0, acc, 0, 0, 0);
                acc = __builtin_amdgcn_mfma_f32_16x16x32_bf16(kf1, qf1, acc, 0, 0, 0);
                s[knt] = acc;
            }
        }
        #pragma unroll
        for (int knt = 0; knt < 8; ++knt) {
            if (knt >= kfull && knt < nkp) {
                const int krow = k0 + knt * 16 + quad * 4;
                #pragma unroll
                for (int r = 0; r < 4; ++r) {
                    float v = (knt < knt_lim) ? s[knt][r] : -1e30f;
                    if (krow + r > qcol) v = -1e30f;
                    s[knt][r] = v;
                }
            }
        }

        unsigned int e0[8], e1[8];
        #pragma unroll
        for (int knt = 0; knt < 8; ++knt) {
            if (knt < nkp) {
                float pv0 = __builtin_amdgcn_exp2f(s[knt][0]);
                float pv1 = __builtin_amdgcn_exp2f(s[knt][1]);
                float pv2 = __builtin_amdgcn_exp2f(s[knt][2]);
                float pv3 = __builtin_amdgcn_exp2f(s[knt][3]);
                lsum += (pv0 + pv1) + (pv2 + pv3);
                unsigned int u0 = __builtin_bit_cast(unsigned int, pv0);
                unsigned int u1 = __builtin_bit_cast(unsigned int, pv1);
                unsigned int u2 = __builtin_bit_cast(unsigned int, pv2);
                unsigned int u3 = __builtin_bit_cast(unsigned int, pv3);
                e0[knt] = ((u0 + 0x8000u) >> 16) | ((u1 + 0x8000u) & 0xffff0000u);
                e1[knt] = ((u2 + 0x8000u) >> 16) | ((u3 + 0x8000u) & 0xffff0000u);
            }
        }

        if (doMid) {
            if (notLast) asm volatile("s_waitcnt vmcnt(4)" ::: "memory");
            else         asm volatile("s_waitcnt vmcnt(0)" ::: "memory");
            __builtin_amdgcn_s_barrier();
        }

        #pragma unroll
        for (int ks = 0; ks < 4; ++ks) {
            if (ks < ks_lim) {
                const int kA = 2 * ks, kB = 2 * ks + 1;
                unsigned int a0 = (unsigned)__shfl((int)e0[kA], sLo);
                unsigned int a1 = (unsigned)__shfl((int)e1[kA], sLo);
                unsigned int a2 = (unsigned)__shfl((int)e0[kA], sHi);
                unsigned int a3 = (unsigned)__shfl((int)e1[kA], sHi);
                unsigned int b0 = (unsigned)__shfl((int)e0[kB], sLo);
                unsigned int b1 = (unsigned)__shfl((int)e1[kB], sLo);
                unsigned int b2 = (unsigned)__shfl((int)e0[kB], sHi);
                unsigned int b3 = (unsigned)__shfl((int)e1[kB], sHi);
                uint4 pu;
                pu.x = hiSel ? b0 : a0;
                pu.y = hiSel ? b1 : a1;
                pu.z = hiSel ? b2 : a2;
                pu.w = hiSel ? b3 : a3;
                bf16x8 pf = __builtin_bit_cast(bf16x8, pu);
                #pragma unroll
                for (int dt = 0; dt < 4; ++dt) {
                    const int row = dt * 16 + n16;
                    bf16x8 vf = *(const bf16x8*)&Vts[row * BKEY +
                                    (((ks * 4 + quad) ^ n16) * 8)];
                    o[dt] = __builtin_amdgcn_mfma_f32_16x16x32_bf16(pf, vf, o[dt], 0, 0, 0);
                }
            }
        }
    };

    stageK(0);
    asm volatile("s_waitcnt vmcnt(0)" ::: "memory");
    __builtin_amdgcn_s_barrier();

    for (int it = 0; it < nIterB; ++it) {
        const int k0 = it * BKEY;
        const bool notLast = (it + 1 < nIterB);

        stageV(it);
        if (notLast) stageK(it + 1);
        const unsigned short* Kb = Ks[it & 1];

        phase(qfB0, qfB1, oB, lsB, wqB, k0, Kb, true,  notLast);
        if (it < nIterA)
            phase(qfA0, qfA1, oA, lsA, wqA, k0, Kb, false, notLast);

        asm volatile("s_waitcnt vmcnt(0)" ::: "memory");
        __builtin_amdgcn_s_barrier();
    }

    lsA += __shfl_xor(lsA, 16); lsA += __shfl_xor(lsA, 32);
    lsB += __shfl_xor(lsB, 16); lsB += __shfl_xor(lsB, 32);

    #pragma unroll
    for (int r = 0; r < 4; ++r) {
        const float invA = 1.f / __shfl(lsA, quad * 4 + r);
        unsigned short* orowA = out + ((size_t)b * T_ + wqA + quad * 4 + r) * E_ + h * D_;
        #pragma unroll
        for (int dt = 0; dt < 4; ++dt)
            orowA[dt * 16 + n16] = f2bf(oA[dt][r] * invA);
        const float invB = 1.f / __shfl(lsB, quad * 4 + r);
        unsigned short* orowB = out + ((size_t)b * T_ + wqB + quad * 4 + r) * E_ + h * D_;
        #pragma unroll
        for (int dt = 0; dt < 4; ++dt)
            orowB[dt * 16 + n16] = f2bf(oB[dt][r] * invB);
    }
}

extern "C" void kernel_launch(void* const* d_in, const int* in_sizes, int n_in,
                              void* d_out, int out_size, void* d_ws, size_t ws_size,
                              hipStream_t stream)
{
    const float* x      = (const float*)d_in[0];
    const float* w_attn = (const float*)d_in[1];
    const float* b_attn = (const float*)d_in[2];
    const float* w_proj = (const float*)d_in[3];
    const float* b_proj = (const float*)d_in[4];
    float* out = (float*)d_out;

    const int M = B_ * T_;  // 8192

    unsigned short* x_bf   = (unsigned short*)d_ws;           // [M,E]
    unsigned short* wat    = x_bf + (size_t)M * E_;           // [3E,E]
    unsigned short* wpt    = wat + (size_t)E3 * E_;           // [E,E]
    unsigned short* qkv_bf = wpt + (size_t)E_ * E_;           // [M,3E] (V region unused)
    unsigned short* att_bf = qkv_bf + (size_t)M * E3;         // [M,E]
    unsigned short* vt_bf  = att_bf + (size_t)M * E_;         // [B*H*64,1024]

    static bool attr_set = false;
    if (!attr_set) {
        (void)hipFuncSetAttribute((const void*)gemm_qkv_128x192,
                                  hipFuncAttributeMaxDynamicSharedMemorySize, 81920);
        attr_set = true;
    }

    prep_kernel<<<NCVT + NTA + NTP, 256, 0, stream>>>(x, x_bf, w_attn, wat, w_proj, wpt);

    gemm_qkv_128x192<<<dim3(768), dim3(512), 81920, stream>>>(
        x_bf, wat, b_attn, qkv_bf, vt_bf);

    flash_attn_kernel<<<B_ * H_ * 8, 256, 0, stream>>>(qkv_bf, vt_bf, att_bf);

    gemm_mfma_kernel<float, 0, 64, 128, 2, 2>
        <<<dim3(E_ / 128, M / 64), 256, 0, stream>>>(
        att_bf, wpt, b_proj, out, nullptr, M, E_, E_);
}